// Round 7
// baseline (196.257 us; speedup 1.0000x reference)
//
#include <hip/hip_runtime.h>
#include <hip/hip_bf16.h>

typedef __attribute__((ext_vector_type(4))) float        f32x4;
typedef __attribute__((ext_vector_type(8))) short        s16x8;
typedef __attribute__((ext_vector_type(4))) unsigned int u32x4;
typedef __attribute__((ext_vector_type(2))) unsigned int u32x2;

#define Bb 8
#define Tt 1024
#define Ss 1024
#define Dd 2048
#define BM 128
#define BN 128
#define BK 64   // K-slab: 2 ks-steps of 32, 32 MFMA/wave/slab

// round-half-up f32 -> bf16, packed pair. Inputs are finite N(0,1); no NaN/Inf path.
__device__ __forceinline__ unsigned pack2_bf16(float f0, float f1) {
  unsigned u0 = __builtin_bit_cast(unsigned, f0) + 0x8000u;
  unsigned u1 = __builtin_bit_cast(unsigned, f1) + 0x8000u;
  return (u0 >> 16) | (u1 & 0xffff0000u);
}

// async global->LDS DMA, 16B/lane. LDS dest = wave-uniform base + lane*16.
__device__ __forceinline__ void gld_lds16(const void* g, void* l) {
  __builtin_amdgcn_global_load_lds(
      (__attribute__((address_space(1))) void*)(void*)(g),
      (__attribute__((address_space(3))) void*)l, 16, 0, 0);
}

// ---------------- Pass 1 v7: DMA-staged fp32 -> bf16 convert + row inv-norm ----
// Root cause of the 6-variant ~3.5 TB/s plateau: register-staged loads get
// serialized by the compiler (r1/r2: VGPR never left 40 despite hoist+fences),
// so each wave holds ~2 loads in flight. global_load_lds is side-effecting and
// CANNOT be sunk — the gemm's staging stream pipelines perfectly for exactly
// this reason. So convert now streams through LDS via DMA:
//   wave owns 1 row per step, 4 rows total; per-wave LDS dbuf ring (2 x 8KB);
//   counted per-wave vmcnt (no barriers at all, LDS regions wave-private).
// vmcnt counts are exact: each region between VWAIT fences contains
// 8 stores + 1 inv store + 8 DMAs; asm memory clobbers pin region boundaries,
// within-region reordering cannot change the counts.
__global__ __launch_bounds__(256, 2)
void convert_kernel(const float* __restrict__ sup, const float* __restrict__ xh,
                    unsigned* __restrict__ abf, unsigned* __restrict__ bbf,
                    float* __restrict__ invA, float* __restrict__ invB)
{
  __shared__ float lds[2][4][2048];          // [slot][wave][row] = 64 KB
  const int t = threadIdx.x, wave = t >> 6, lane = t & 63;
  const int wbase = (blockIdx.x * 4 + wave) * 4;   // 1024 blocks * 4 waves * 4 rows = 16384

  // wave's 4 rows are one tensor (8192 % 4 == 0, no crossing)
  const float* src; unsigned* dst; float* inv; int row0;
  if (wbase < 8192) { src = xh;  dst = abf; inv = invA; row0 = wbase; }
  else              { src = sup; dst = bbf; inv = invB; row0 = wbase - 8192; }

#define STAGE(slot, r) do {                                              \
    const float* gp = src + (size_t)(row0 + (r)) * Dd + lane * 4;        \
    float* lp = &lds[slot][wave][0];                                     \
    _Pragma("unroll")                                                    \
    for (int i = 0; i < 8; ++i)                                          \
      gld_lds16(gp + i * 256, lp + i * 256);                             \
  } while (0)

#define PROCESS(slot, r) do {                                            \
    const float* L = &lds[slot][wave][0];                                \
    unsigned* drow = dst + (size_t)(row0 + (r)) * (Dd / 2);              \
    float sq = 0.0f;                                                     \
    _Pragma("unroll")                                                    \
    for (int i = 0; i < 8; ++i) {                                        \
      f32x4 v = *(const f32x4*)(L + i * 256 + lane * 4);                 \
      sq = fmaf(v[0], v[0], fmaf(v[1], v[1], fmaf(v[2], v[2], fmaf(v[3], v[3], sq)))); \
      *(u32x2*)(drow + i * 128 + lane * 2) =                             \
          (u32x2){pack2_bf16(v[0], v[1]), pack2_bf16(v[2], v[3])};       \
    }                                                                    \
    _Pragma("unroll")                                                    \
    for (int m = 32; m; m >>= 1) sq += __shfl_xor(sq, m, 64);            \
    if (lane == 0) inv[row0 + (r)] = 1.0f / sqrtf(sq);                   \
  } while (0)

#define VWAIT(n) do {                                                    \
    asm volatile("s_waitcnt vmcnt(" #n ")" ::: "memory");                \
    __builtin_amdgcn_sched_barrier(0);                                   \
  } while (0)

  // pipeline: stage r0,r1; process r0 | stage r2; process r1 | stage r3; ...
  STAGE(0, 0);                 // 8 DMAs (slot0)
  STAGE(1, 1);                 // 8 DMAs (slot1)
  VWAIT(8);  PROCESS(0, 0);    // 8 newer ops (slot1 DMAs) -> slot0 landed
  STAGE(0, 2);
  VWAIT(17); PROCESS(1, 1);    // after slot1: 8 st + 1 inv + 8 DMA = 17
  STAGE(1, 3);
  VWAIT(17); PROCESS(0, 2);    // after slot0(r2): 8 st + 1 inv + 8 DMA = 17
  VWAIT(9);  PROCESS(1, 3);    // after slot1(r3): 8 st + 1 inv = 9
#undef STAGE
#undef PROCESS
#undef VWAIT
}

// ---------------- Pass 2: bf16 GEMM — EXACT r4 version (proven 42.9 us) ----------------
// r5 erratum: the "LDS-BW-bound" arithmetic was wrong (actual ~50 B/cyc of 85
// achievable). gemm is schedule-bound at ~800 TF; structural escapes (256^2
// 8-phase -> 128 blocks = half CUs idle; split-K -> +16us reduce) net ~0 for
// this shape. Kept as local optimum of its class.
// T4 counted-vmcnt: s_barrier + s_waitcnt vmcnt(8), never drain to 0 mid-loop.
// T1 XCD swizzle: grid=512=8*64 bijective. XOR swizzle on 16B chunks (0 conflicts).
__global__ __launch_bounds__(256, 2)
void gemm_kernel(const short* __restrict__ abf, const short* __restrict__ bbf,
                 const float* __restrict__ invA, const float* __restrict__ invB,
                 float* __restrict__ out)
{
  __shared__ short As[2][BM * BK];   // 2 x 16 KB
  __shared__ short Bs[2][BN * BK];   // 2 x 16 KB

  const int bid0 = blockIdx.x;
  const int bid  = ((bid0 & 7) << 6) | (bid0 >> 3);   // T1: XCD-contiguous remap
  const int b    = bid >> 6;
  const int tile = bid & 63;
  const int tm   = tile >> 3;
  const int tn   = tile & 7;

  const int t = threadIdx.x, wave = t >> 6, lane = t & 63;

  const int srow = lane >> 3;
  const int cph  = lane & 7;
  const int r0   = wave * 32;

  const size_t aRow = (size_t)(b * Tt + tm * BM);
  const size_t bRow = (size_t)(b * Ss + tn * BN);
  const short *gA0, *gA1, *gA2, *gA3, *gB0, *gB1, *gB2, *gB3;
  {
    int r;
    r = r0 + 0 * 8 + srow; gA0 = abf + (aRow + r) * Dd + (cph ^ (r & 7)) * 8;
                           gB0 = bbf + (bRow + r) * Dd + (cph ^ (r & 7)) * 8;
    r = r0 + 1 * 8 + srow; gA1 = abf + (aRow + r) * Dd + (cph ^ (r & 7)) * 8;
                           gB1 = bbf + (bRow + r) * Dd + (cph ^ (r & 7)) * 8;
    r = r0 + 2 * 8 + srow; gA2 = abf + (aRow + r) * Dd + (cph ^ (r & 7)) * 8;
                           gB2 = bbf + (bRow + r) * Dd + (cph ^ (r & 7)) * 8;
    r = r0 + 3 * 8 + srow; gA3 = abf + (aRow + r) * Dd + (cph ^ (r & 7)) * 8;
                           gB3 = bbf + (bRow + r) * Dd + (cph ^ (r & 7)) * 8;
  }

  const int wm = (wave >> 1) << 6;
  const int wn = (wave & 1) << 6;
  const int lm = lane & 15;
  const int kq = lane >> 4;

  f32x4 acc[4][4];
  #pragma unroll
  for (int i = 0; i < 4; ++i)
    #pragma unroll
    for (int j = 0; j < 4; ++j)
      acc[i][j] = (f32x4)0.0f;

#define STAGE(bi) do {                                                   \
    gld_lds16(gA0, As[bi] + (r0 + 0)  * BK);                             \
    gld_lds16(gA1, As[bi] + (r0 + 8)  * BK);                             \
    gld_lds16(gA2, As[bi] + (r0 + 16) * BK);                             \
    gld_lds16(gA3, As[bi] + (r0 + 24) * BK);                             \
    gld_lds16(gB0, Bs[bi] + (r0 + 0)  * BK);                             \
    gld_lds16(gB1, Bs[bi] + (r0 + 8)  * BK);                             \
    gld_lds16(gB2, Bs[bi] + (r0 + 16) * BK);                             \
    gld_lds16(gB3, Bs[bi] + (r0 + 24) * BK);                             \
    gA0 += BK; gA1 += BK; gA2 += BK; gA3 += BK;                          \
    gB0 += BK; gB1 += BK; gB2 += BK; gB3 += BK;                          \
  } while (0)

#define COMPUTE(bi) do {                                                 \
    _Pragma("unroll")                                                    \
    for (int ks = 0; ks < 2; ++ks) {                                     \
      const int pchunk = ((ks * 4 + kq) ^ (lm & 7)) * 8;                 \
      s16x8 af[4], bfr[4];                                               \
      _Pragma("unroll")                                                  \
      for (int i = 0; i < 4; ++i) {                                      \
        af[i]  = *(const s16x8*)(As[bi] + (wm + i * 16 + lm) * BK + pchunk); \
        bfr[i] = *(const s16x8*)(Bs[bi] + (wn + i * 16 + lm) * BK + pchunk); \
      }                                                                  \
      _Pragma("unroll")                                                  \
      for (int mi = 0; mi < 4; ++mi)                                     \
        _Pragma("unroll")                                                \
        for (int ni = 0; ni < 4; ++ni)                                   \
          acc[mi][ni] = __builtin_amdgcn_mfma_f32_16x16x32_bf16(af[mi], bfr[ni], acc[mi][ni], 0, 0, 0); \
    }                                                                    \
  } while (0)

#define WAIT_BAR(n) do {                                                 \
    asm volatile("s_waitcnt vmcnt(" #n ")" ::: "memory");                \
    __builtin_amdgcn_s_barrier();                                        \
    __builtin_amdgcn_sched_barrier(0);                                   \
  } while (0)

  // prologue: slabs 0,1 in flight (16 outstanding)
  STAGE(0);
  STAGE(1);

  // steady: 15 iterations x 2 slabs = slabs 0..29; stages slabs 2..31.
  for (int i = 0; i < 15; ++i) {
    WAIT_BAR(8);                   // buffer0 slab landed (8 newer still flying)
    COMPUTE(0);
    __builtin_amdgcn_sched_barrier(0);
    __builtin_amdgcn_s_barrier();  // all waves done reading buffer0
    STAGE(0);                      // slab 2i+2 -> 16 outstanding
    WAIT_BAR(8);                   // buffer1 slab landed
    COMPUTE(1);
    __builtin_amdgcn_sched_barrier(0);
    __builtin_amdgcn_s_barrier();  // all waves done reading buffer1
    STAGE(1);                      // slab 2i+3 -> 16 outstanding
  }

  // epilogue: slabs 30 (buffer0), 31 (buffer1).
  WAIT_BAR(8);
  COMPUTE(0);
  WAIT_BAR(0);                     // final buffer needs a full wait
  COMPUTE(1);
#undef STAGE
#undef COMPUTE
#undef WAIT_BAR

  const float* iA = invA + b * Tt + tm * BM;
  const float* iB = invB + b * Ss + tn * BN;
  float* outb = out + (size_t)(b * Tt + tm * BM) * Ss + tn * BN;
  const int m0 = wm + kq * 4;
  const int n0 = wn + lm;
  #pragma unroll
  for (int mi = 0; mi < 4; ++mi) {
    #pragma unroll
    for (int r = 0; r < 4; ++r) {
      const int mrow = m0 + mi * 16 + r;
      const float ia = iA[mrow];
      float* orow = outb + (size_t)mrow * Ss;
      #pragma unroll
      for (int ni = 0; ni < 4; ++ni) {
        const int ncol = n0 + ni * 16;
        orow[ncol] = acc[mi][ni][r] * (ia * iB[ncol]);
      }
    }
  }
}

// ---------------- Fallback: round-1 fused kernel (used only if ws too small) ----------------
#define LDKF 40
#define BKF 32
__global__ __launch_bounds__(256, 2)
void paircos_kernel(const float* __restrict__ sup, const float* __restrict__ xh,
                    float* __restrict__ out)
{
  __shared__ short As[BM * LDKF];
  __shared__ short Bs[BN * LDKF];
  __shared__ float invA[BM];
  __shared__ float invB[BN];

  const int bid = blockIdx.x;
  const int b = bid >> 6, tile = bid & 63, tm = tile >> 3, tn = tile & 7;
  const float* Abase = xh  + (size_t)(b * Tt + tm * BM) * Dd;
  const float* Bbase = sup + (size_t)(b * Ss + tn * BN) * Dd;
  const int t = threadIdx.x, row = t >> 1, kh = t & 1;
  const f32x4* agp = (const f32x4*)(Abase + (size_t)row * Dd + kh * 16);
  const f32x4* bgp = (const f32x4*)(Bbase + (size_t)row * Dd + kh * 16);
  u32x4* awr = (u32x4*)(As + row * LDKF + kh * 16);
  u32x4* bwr = (u32x4*)(Bs + row * LDKF + kh * 16);
  const int wave = t >> 6, lane = t & 63;
  const int wm = (wave >> 1) << 6, wn = (wave & 1) << 6;
  const int lm = lane & 15, kq = lane >> 4;

  f32x4 acc[4][4];
  #pragma unroll
  for (int i = 0; i < 4; ++i)
    #pragma unroll
    for (int j = 0; j < 4; ++j) acc[i][j] = (f32x4)0.0f;
  float sqa = 0.0f, sqb = 0.0f;
  f32x4 areg[4], breg[4];
  #pragma unroll
  for (int i = 0; i < 4; ++i) { areg[i] = agp[i]; breg[i] = bgp[i]; }

  for (int k0 = 0; k0 < Dd; k0 += BKF) {
    unsigned pa[8], pb[8];
    #pragma unroll
    for (int i = 0; i < 4; ++i) {
      sqa = fmaf(areg[i][0], areg[i][0], sqa); sqa = fmaf(areg[i][1], areg[i][1], sqa);
      sqa = fmaf(areg[i][2], areg[i][2], sqa); sqa = fmaf(areg[i][3], areg[i][3], sqa);
      pa[i*2+0] = pack2_bf16(areg[i][0], areg[i][1]); pa[i*2+1] = pack2_bf16(areg[i][2], areg[i][3]);
      sqb = fmaf(breg[i][0], breg[i][0], sqb); sqb = fmaf(breg[i][1], breg[i][1], sqb);
      sqb = fmaf(breg[i][2], breg[i][2], sqb); sqb = fmaf(breg[i][3], breg[i][3], sqb);
      pb[i*2+0] = pack2_bf16(breg[i][0], breg[i][1]); pb[i*2+1] = pack2_bf16(breg[i][2], breg[i][3]);
    }
    __syncthreads();
    awr[0] = (u32x4){pa[0],pa[1],pa[2],pa[3]}; awr[1] = (u32x4){pa[4],pa[5],pa[6],pa[7]};
    bwr[0] = (u32x4){pb[0],pb[1],pb[2],pb[3]}; bwr[1] = (u32x4){pb[4],pb[5],pb[6],pb[7]};
    __syncthreads();
    if (k0 + BKF < Dd) {
      const int off = (k0 + BKF) >> 2;
      #pragma unroll
      for (int i = 0; i < 4; ++i) { areg[i] = agp[off + i]; breg[i] = bgp[off + i]; }
    }
    s16x8 af[4], bfr[4];
    #pragma unroll
    for (int i = 0; i < 4; ++i) {
      af[i]  = *(const s16x8*)(As + (wm + i*16 + lm) * LDKF + kq * 8);
      bfr[i] = *(const s16x8*)(Bs + (wn + i*16 + lm) * LDKF + kq * 8);
    }
    #pragma unroll
    for (int mi = 0; mi < 4; ++mi)
      #pragma unroll
      for (int ni = 0; ni < 4; ++ni)
        acc[mi][ni] = __builtin_amdgcn_mfma_f32_16x16x32_bf16(af[mi], bfr[ni], acc[mi][ni], 0, 0, 0);
  }
  __syncthreads();
  ((float*)As)[t] = sqa; ((float*)Bs)[t] = sqb;
  __syncthreads();
  if (t < 128) {
    invA[t] = 1.0f / sqrtf(((float*)As)[2*t] + ((float*)As)[2*t+1]);
    invB[t] = 1.0f / sqrtf(((float*)Bs)[2*t] + ((float*)Bs)[2*t+1]);
  }
  __syncthreads();
  float* outb = out + (size_t)(b * Tt + tm * BM) * Ss + tn * BN;
  const int m0 = wm + kq * 4, n0 = wn + lm;
  #pragma unroll
  for (int mi = 0; mi < 4; ++mi) {
    #pragma unroll
    for (int r = 0; r < 4; ++r) {
      const int mrow = m0 + mi * 16 + r;
      const float ia = invA[mrow];
      float* orow = outb + (size_t)mrow * Ss;
      #pragma unroll
      for (int ni = 0; ni < 4; ++ni) {
        const int ncol = n0 + ni * 16;
        orow[ncol] = acc[mi][ni][r] * (ia * invB[ncol]);
      }
    }
  }
}

extern "C" void kernel_launch(void* const* d_in, const int* in_sizes, int n_in,
                              void* d_out, int out_size, void* d_ws, size_t ws_size,
                              hipStream_t stream) {
  const float* sup = (const float*)d_in[0];  // support_sets [8,1024,2048]
  const float* xh  = (const float*)d_in[1];  // X_hats       [8,1024,2048]
  float* out = (float*)d_out;                // [8,1024,1024] fp32

  const size_t nElem = (size_t)Bb * Tt * Dd;              // 16.78M per tensor
  const size_t bfBytes = nElem * sizeof(short);           // 33.55 MB
  const size_t NEED = 2 * bfBytes + 2 * (size_t)Bb * Tt * sizeof(float);

  if (ws_size >= NEED) {
    unsigned* abf = (unsigned*)d_ws;
    unsigned* bbf = (unsigned*)((char*)d_ws + bfBytes);
    float* invA = (float*)((char*)d_ws + 2 * bfBytes);
    float* invB = invA + (size_t)Bb * Tt;
    convert_kernel<<<dim3(1024), dim3(256), 0, stream>>>(sup, xh, abf, bbf, invA, invB);
    gemm_kernel<<<dim3(512), dim3(256), 0, stream>>>((const short*)abf, (const short*)bbf,
                                                     invA, invB, out);
  } else {
    paircos_kernel<<<dim3(512), dim3(256), 0, stream>>>(sup, xh, out);
  }
}

// Round 8
// 196.200 us; speedup vs baseline: 1.0003x; 1.0003x over previous
//
#include <hip/hip_runtime.h>
#include <hip/hip_bf16.h>

typedef __attribute__((ext_vector_type(4))) float        f32x4;
typedef __attribute__((ext_vector_type(8))) short        s16x8;
typedef __attribute__((ext_vector_type(4))) unsigned int u32x4;
typedef __attribute__((ext_vector_type(2))) unsigned int u32x2;

#define Bb 8
#define Tt 1024
#define Ss 1024
#define Dd 2048
#define BM 128
#define BN 128
#define BK 64   // K-slab: 2 ks-steps of 32, 32 MFMA/wave/slab

// round-half-up f32 -> bf16, packed pair. Inputs are finite N(0,1); no NaN/Inf path.
__device__ __forceinline__ unsigned pack2_bf16(float f0, float f1) {
  unsigned u0 = __builtin_bit_cast(unsigned, f0) + 0x8000u;
  unsigned u1 = __builtin_bit_cast(unsigned, f1) + 0x8000u;
  return (u0 >> 16) | (u1 & 0xffff0000u);
}

// async global->LDS DMA, 16B/lane. LDS dest = wave-uniform base + lane*16.
__device__ __forceinline__ void gld_lds16(const void* g, void* l) {
  __builtin_amdgcn_global_load_lds(
      (__attribute__((address_space(1))) void*)(void*)(g),
      (__attribute__((address_space(3))) void*)l, 16, 0, 0);
}

// ---------------- Pass 1 v8: r6 body + grid-stride (block churn fix) ----------------
// r7 DMA-ring verdict: regressed 54->65us (occupancy 61->18%; traded TLP for a
// serial per-wave pipeline). Reverted to the r6 high-TLP body — best measured
// (53.5-55.7us, occ 61%, VGPR 12, nothing saturated). Remaining lever per
// Guideline 11: 16384 one-shot blocks churn waves (~1us lifetime, constant
// drain/refill -> occ stuck at 61%). Grid-stride: 2048 resident blocks x 8
// row-slots each; same memory pattern, same TLP, 8x less block setup/drain.
__global__ __launch_bounds__(256, 8)
void convert_kernel(const float* __restrict__ sup, const float* __restrict__ xh,
                    unsigned* __restrict__ abf, unsigned* __restrict__ bbf,
                    float* __restrict__ invA, float* __restrict__ invB)
{
  __shared__ float red[4];
  const int t = threadIdx.x;               // 0..255
  const int wave = t >> 6, lane = t & 63;

  #pragma unroll
  for (int it = 0; it < 8; ++it) {
    const int slot = blockIdx.x + (it << 11);   // 0..16383, stride 2048
    const int row  = slot & 8191;
    const float* src; unsigned* dst; float* inv;
    if (slot < 8192) { src = xh;  dst = abf; inv = invA; }
    else             { src = sup; dst = bbf; inv = invB; }

    const f32x4* s = (const f32x4*)(src + (size_t)row * Dd);
    const f32x4 a = s[t];                  // elements [4t, 4t+4)
    const f32x4 b = s[256 + t];            // elements [1024+4t, ...)

    float sq = fmaf(a[0], a[0], fmaf(a[1], a[1], fmaf(a[2], a[2], a[3] * a[3])));
    sq = fmaf(b[0], b[0], fmaf(b[1], b[1], fmaf(b[2], b[2], fmaf(b[3], b[3], sq))));

    u32x2* d = (u32x2*)(dst + (size_t)row * (Dd / 2));
    d[t]       = (u32x2){pack2_bf16(a[0], a[1]), pack2_bf16(a[2], a[3])};
    d[256 + t] = (u32x2){pack2_bf16(b[0], b[1]), pack2_bf16(b[2], b[3])};

    #pragma unroll
    for (int m = 32; m; m >>= 1) sq += __shfl_xor(sq, m, 64);
    if (lane == 0) red[wave] = sq;
    __syncthreads();
    if (t == 0) inv[row] = 1.0f / sqrtf(red[0] + red[1] + red[2] + red[3]);
    __syncthreads();                       // red[] reused next iteration
  }
}

// ---------------- Pass 2: bf16 GEMM — EXACT r4 version (proven 42.9 us) ----------------
// Schedule-bound local optimum of the 128^2 2-phase class (~800 TF, MfmaUtil 29%).
// Structural escapes priced and rejected for this shape: 256^2 8-phase -> 128
// blocks (half CUs idle, r5 regression); split-K -> +16us fp32 reduce.
// T4 counted-vmcnt: s_barrier + s_waitcnt vmcnt(8), never drain to 0 mid-loop.
// T1 XCD swizzle: grid=512=8*64 bijective. XOR swizzle on 16B chunks (0 conflicts).
__global__ __launch_bounds__(256, 2)
void gemm_kernel(const short* __restrict__ abf, const short* __restrict__ bbf,
                 const float* __restrict__ invA, const float* __restrict__ invB,
                 float* __restrict__ out)
{
  __shared__ short As[2][BM * BK];   // 2 x 16 KB
  __shared__ short Bs[2][BN * BK];   // 2 x 16 KB

  const int bid0 = blockIdx.x;
  const int bid  = ((bid0 & 7) << 6) | (bid0 >> 3);   // T1: XCD-contiguous remap
  const int b    = bid >> 6;
  const int tile = bid & 63;
  const int tm   = tile >> 3;
  const int tn   = tile & 7;

  const int t = threadIdx.x, wave = t >> 6, lane = t & 63;

  const int srow = lane >> 3;
  const int cph  = lane & 7;
  const int r0   = wave * 32;

  const size_t aRow = (size_t)(b * Tt + tm * BM);
  const size_t bRow = (size_t)(b * Ss + tn * BN);
  const short *gA0, *gA1, *gA2, *gA3, *gB0, *gB1, *gB2, *gB3;
  {
    int r;
    r = r0 + 0 * 8 + srow; gA0 = abf + (aRow + r) * Dd + (cph ^ (r & 7)) * 8;
                           gB0 = bbf + (bRow + r) * Dd + (cph ^ (r & 7)) * 8;
    r = r0 + 1 * 8 + srow; gA1 = abf + (aRow + r) * Dd + (cph ^ (r & 7)) * 8;
                           gB1 = bbf + (bRow + r) * Dd + (cph ^ (r & 7)) * 8;
    r = r0 + 2 * 8 + srow; gA2 = abf + (aRow + r) * Dd + (cph ^ (r & 7)) * 8;
                           gB2 = bbf + (bRow + r) * Dd + (cph ^ (r & 7)) * 8;
    r = r0 + 3 * 8 + srow; gA3 = abf + (aRow + r) * Dd + (cph ^ (r & 7)) * 8;
                           gB3 = bbf + (bRow + r) * Dd + (cph ^ (r & 7)) * 8;
  }

  const int wm = (wave >> 1) << 6;
  const int wn = (wave & 1) << 6;
  const int lm = lane & 15;
  const int kq = lane >> 4;

  f32x4 acc[4][4];
  #pragma unroll
  for (int i = 0; i < 4; ++i)
    #pragma unroll
    for (int j = 0; j < 4; ++j)
      acc[i][j] = (f32x4)0.0f;

#define STAGE(bi) do {                                                   \
    gld_lds16(gA0, As[bi] + (r0 + 0)  * BK);                             \
    gld_lds16(gA1, As[bi] + (r0 + 8)  * BK);                             \
    gld_lds16(gA2, As[bi] + (r0 + 16) * BK);                             \
    gld_lds16(gA3, As[bi] + (r0 + 24) * BK);                             \
    gld_lds16(gB0, Bs[bi] + (r0 + 0)  * BK);                             \
    gld_lds16(gB1, Bs[bi] + (r0 + 8)  * BK);                             \
    gld_lds16(gB2, Bs[bi] + (r0 + 16) * BK);                             \
    gld_lds16(gB3, Bs[bi] + (r0 + 24) * BK);                             \
    gA0 += BK; gA1 += BK; gA2 += BK; gA3 += BK;                          \
    gB0 += BK; gB1 += BK; gB2 += BK; gB3 += BK;                          \
  } while (0)

#define COMPUTE(bi) do {                                                 \
    _Pragma("unroll")                                                    \
    for (int ks = 0; ks < 2; ++ks) {                                     \
      const int pchunk = ((ks * 4 + kq) ^ (lm & 7)) * 8;                 \
      s16x8 af[4], bfr[4];                                               \
      _Pragma("unroll")                                                  \
      for (int i = 0; i < 4; ++i) {                                      \
        af[i]  = *(const s16x8*)(As[bi] + (wm + i * 16 + lm) * BK + pchunk); \
        bfr[i] = *(const s16x8*)(Bs[bi] + (wn + i * 16 + lm) * BK + pchunk); \
      }                                                                  \
      _Pragma("unroll")                                                  \
      for (int mi = 0; mi < 4; ++mi)                                     \
        _Pragma("unroll")                                                \
        for (int ni = 0; ni < 4; ++ni)                                   \
          acc[mi][ni] = __builtin_amdgcn_mfma_f32_16x16x32_bf16(af[mi], bfr[ni], acc[mi][ni], 0, 0, 0); \
    }                                                                    \
  } while (0)

#define WAIT_BAR(n) do {                                                 \
    asm volatile("s_waitcnt vmcnt(" #n ")" ::: "memory");                \
    __builtin_amdgcn_s_barrier();                                        \
    __builtin_amdgcn_sched_barrier(0);                                   \
  } while (0)

  // prologue: slabs 0,1 in flight (16 outstanding)
  STAGE(0);
  STAGE(1);

  // steady: 15 iterations x 2 slabs = slabs 0..29; stages slabs 2..31.
  for (int i = 0; i < 15; ++i) {
    WAIT_BAR(8);                   // buffer0 slab landed (8 newer still flying)
    COMPUTE(0);
    __builtin_amdgcn_sched_barrier(0);
    __builtin_amdgcn_s_barrier();  // all waves done reading buffer0
    STAGE(0);                      // slab 2i+2 -> 16 outstanding
    WAIT_BAR(8);                   // buffer1 slab landed
    COMPUTE(1);
    __builtin_amdgcn_sched_barrier(0);
    __builtin_amdgcn_s_barrier();  // all waves done reading buffer1
    STAGE(1);                      // slab 2i+3 -> 16 outstanding
  }

  // epilogue: slabs 30 (buffer0), 31 (buffer1).
  WAIT_BAR(8);
  COMPUTE(0);
  WAIT_BAR(0);                     // final buffer needs a full wait
  COMPUTE(1);
#undef STAGE
#undef COMPUTE
#undef WAIT_BAR

  const float* iA = invA + b * Tt + tm * BM;
  const float* iB = invB + b * Ss + tn * BN;
  float* outb = out + (size_t)(b * Tt + tm * BM) * Ss + tn * BN;
  const int m0 = wm + kq * 4;
  const int n0 = wn + lm;
  #pragma unroll
  for (int mi = 0; mi < 4; ++mi) {
    #pragma unroll
    for (int r = 0; r < 4; ++r) {
      const int mrow = m0 + mi * 16 + r;
      const float ia = iA[mrow];
      float* orow = outb + (size_t)mrow * Ss;
      #pragma unroll
      for (int ni = 0; ni < 4; ++ni) {
        const int ncol = n0 + ni * 16;
        orow[ncol] = acc[mi][ni][r] * (ia * iB[ncol]);
      }
    }
  }
}

// ---------------- Fallback: round-1 fused kernel (used only if ws too small) ----------------
#define LDKF 40
#define BKF 32
__global__ __launch_bounds__(256, 2)
void paircos_kernel(const float* __restrict__ sup, const float* __restrict__ xh,
                    float* __restrict__ out)
{
  __shared__ short As[BM * LDKF];
  __shared__ short Bs[BN * LDKF];
  __shared__ float invA[BM];
  __shared__ float invB[BN];

  const int bid = blockIdx.x;
  const int b = bid >> 6, tile = bid & 63, tm = tile >> 3, tn = tile & 7;
  const float* Abase = xh  + (size_t)(b * Tt + tm * BM) * Dd;
  const float* Bbase = sup + (size_t)(b * Ss + tn * BN) * Dd;
  const int t = threadIdx.x, row = t >> 1, kh = t & 1;
  const f32x4* agp = (const f32x4*)(Abase + (size_t)row * Dd + kh * 16);
  const f32x4* bgp = (const f32x4*)(Bbase + (size_t)row * Dd + kh * 16);
  u32x4* awr = (u32x4*)(As + row * LDKF + kh * 16);
  u32x4* bwr = (u32x4*)(Bs + row * LDKF + kh * 16);
  const int wave = t >> 6, lane = t & 63;
  const int wm = (wave >> 1) << 6, wn = (wave & 1) << 6;
  const int lm = lane & 15, kq = lane >> 4;

  f32x4 acc[4][4];
  #pragma unroll
  for (int i = 0; i < 4; ++i)
    #pragma unroll
    for (int j = 0; j < 4; ++j) acc[i][j] = (f32x4)0.0f;
  float sqa = 0.0f, sqb = 0.0f;
  f32x4 areg[4], breg[4];
  #pragma unroll
  for (int i = 0; i < 4; ++i) { areg[i] = agp[i]; breg[i] = bgp[i]; }

  for (int k0 = 0; k0 < Dd; k0 += BKF) {
    unsigned pa[8], pb[8];
    #pragma unroll
    for (int i = 0; i < 4; ++i) {
      sqa = fmaf(areg[i][0], areg[i][0], sqa); sqa = fmaf(areg[i][1], areg[i][1], sqa);
      sqa = fmaf(areg[i][2], areg[i][2], sqa); sqa = fmaf(areg[i][3], areg[i][3], sqa);
      pa[i*2+0] = pack2_bf16(areg[i][0], areg[i][1]); pa[i*2+1] = pack2_bf16(areg[i][2], areg[i][3]);
      sqb = fmaf(breg[i][0], breg[i][0], sqb); sqb = fmaf(breg[i][1], breg[i][1], sqb);
      sqb = fmaf(breg[i][2], breg[i][2], sqb); sqb = fmaf(breg[i][3], breg[i][3], sqb);
      pb[i*2+0] = pack2_bf16(breg[i][0], breg[i][1]); pb[i*2+1] = pack2_bf16(breg[i][2], breg[i][3]);
    }
    __syncthreads();
    awr[0] = (u32x4){pa[0],pa[1],pa[2],pa[3]}; awr[1] = (u32x4){pa[4],pa[5],pa[6],pa[7]};
    bwr[0] = (u32x4){pb[0],pb[1],pb[2],pb[3]}; bwr[1] = (u32x4){pb[4],pb[5],pb[6],pb[7]};
    __syncthreads();
    if (k0 + BKF < Dd) {
      const int off = (k0 + BKF) >> 2;
      #pragma unroll
      for (int i = 0; i < 4; ++i) { areg[i] = agp[off + i]; breg[i] = bgp[off + i]; }
    }
    s16x8 af[4], bfr[4];
    #pragma unroll
    for (int i = 0; i < 4; ++i) {
      af[i]  = *(const s16x8*)(As + (wm + i*16 + lm) * LDKF + kq * 8);
      bfr[i] = *(const s16x8*)(Bs + (wn + i*16 + lm) * LDKF + kq * 8);
    }
    #pragma unroll
    for (int mi = 0; mi < 4; ++mi)
      #pragma unroll
      for (int ni = 0; ni < 4; ++ni)
        acc[mi][ni] = __builtin_amdgcn_mfma_f32_16x16x32_bf16(af[mi], bfr[ni], acc[mi][ni], 0, 0, 0);
  }
  __syncthreads();
  ((float*)As)[t] = sqa; ((float*)Bs)[t] = sqb;
  __syncthreads();
  if (t < 128) {
    invA[t] = 1.0f / sqrtf(((float*)As)[2*t] + ((float*)As)[2*t+1]);
    invB[t] = 1.0f / sqrtf(((float*)Bs)[2*t] + ((float*)Bs)[2*t+1]);
  }
  __syncthreads();
  float* outb = out + (size_t)(b * Tt + tm * BM) * Ss + tn * BN;
  const int m0 = wm + kq * 4, n0 = wn + lm;
  #pragma unroll
  for (int mi = 0; mi < 4; ++mi) {
    #pragma unroll
    for (int r = 0; r < 4; ++r) {
      const int mrow = m0 + mi * 16 + r;
      const float ia = invA[mrow];
      float* orow = outb + (size_t)mrow * Ss;
      #pragma unroll
      for (int ni = 0; ni < 4; ++ni) {
        const int ncol = n0 + ni * 16;
        orow[ncol] = acc[mi][ni][r] * (ia * invB[ncol]);
      }
    }
  }
}

extern "C" void kernel_launch(void* const* d_in, const int* in_sizes, int n_in,
                              void* d_out, int out_size, void* d_ws, size_t ws_size,
                              hipStream_t stream) {
  const float* sup = (const float*)d_in[0];  // support_sets [8,1024,2048]
  const float* xh  = (const float*)d_in[1];  // X_hats       [8,1024,2048]
  float* out = (float*)d_out;                // [8,1024,1024] fp32

  const size_t nElem = (size_t)Bb * Tt * Dd;              // 16.78M per tensor
  const size_t bfBytes = nElem * sizeof(short);           // 33.55 MB
  const size_t NEED = 2 * bfBytes + 2 * (size_t)Bb * Tt * sizeof(float);

  if (ws_size >= NEED) {
    unsigned* abf = (unsigned*)d_ws;
    unsigned* bbf = (unsigned*)((char*)d_ws + bfBytes);
    float* invA = (float*)((char*)d_ws + 2 * bfBytes);
    float* invB = invA + (size_t)Bb * Tt;
    convert_kernel<<<dim3(2048), dim3(256), 0, stream>>>(sup, xh, abf, bbf, invA, invB);
    gemm_kernel<<<dim3(512), dim3(256), 0, stream>>>((const short*)abf, (const short*)bbf,
                                                     invA, invB, out);
  } else {
    paircos_kernel<<<dim3(512), dim3(256), 0, stream>>>(sup, xh, out);
  }
}

// Round 9
// 191.800 us; speedup vs baseline: 1.0232x; 1.0229x over previous
//
#include <hip/hip_runtime.h>
#include <hip/hip_bf16.h>

typedef __attribute__((ext_vector_type(4))) float        f32x4;
typedef __attribute__((ext_vector_type(8))) short        s16x8;
typedef __attribute__((ext_vector_type(4))) unsigned int u32x4;
typedef __attribute__((ext_vector_type(2))) unsigned int u32x2;

#define Bb 8
#define Tt 1024
#define Ss 1024
#define Dd 2048
#define BM 128
#define BN 128
#define BK 64   // K-slab: 2 ks-steps of 32, 32 MFMA/wave/slab

// round-half-up f32 -> bf16, packed pair. Inputs are finite N(0,1); no NaN/Inf path.
__device__ __forceinline__ unsigned pack2_bf16(float f0, float f1) {
  unsigned u0 = __builtin_bit_cast(unsigned, f0) + 0x8000u;
  unsigned u1 = __builtin_bit_cast(unsigned, f1) + 0x8000u;
  return (u0 >> 16) | (u1 & 0xffff0000u);
}

// async global->LDS DMA, 16B/lane. LDS dest = wave-uniform base + lane*16.
__device__ __forceinline__ void gld_lds16(const void* g, void* l) {
  __builtin_amdgcn_global_load_lds(
      (__attribute__((address_space(1))) void*)(void*)(g),
      (__attribute__((address_space(3))) void*)l, 16, 0, 0);
}

// ---------------- Pass 1: fp32 -> bf16 convert + row inv-norm (r6 best: ~54us) ----
// FINAL after 8 structural variants (scalar-ILP / reg-hoist / fenced-hoist /
// max-TLP / coalesced-unified / DMA-ring / grid-stride) all in 54-66us:
// mixed 134MB-read + 67MB-write stream plateaus at ~3.5-3.7 TB/s demand with NO
// counter saturated (HBM 31%, VALU 13%, occ 61%, VGPR 12) -> stream-mix bound.
// One row per block, one-shot grid (16384 blocks). Fully coalesced: 16B/lane
// loads, 8B/lane stores. Wave shuffle-reduce + tiny LDS cross-wave reduce.
__global__ __launch_bounds__(256, 8)
void convert_kernel(const float* __restrict__ sup, const float* __restrict__ xh,
                    unsigned* __restrict__ abf, unsigned* __restrict__ bbf,
                    float* __restrict__ invA, float* __restrict__ invB)
{
  __shared__ float red[4];
  const int bid = blockIdx.x;              // 0..16383
  const int row = bid & 8191;
  const float* src; unsigned* dst; float* inv;
  if (bid < 8192) { src = xh;  dst = abf; inv = invA; }
  else            { src = sup; dst = bbf; inv = invB; }

  const int t = threadIdx.x;               // 0..255
  const f32x4* s = (const f32x4*)(src + (size_t)row * Dd);
  const f32x4 a = s[t];                    // elements [4t, 4t+4)
  const f32x4 b = s[256 + t];              // elements [1024+4t, ...)

  float sq = fmaf(a[0], a[0], fmaf(a[1], a[1], fmaf(a[2], a[2], a[3] * a[3])));
  sq = fmaf(b[0], b[0], fmaf(b[1], b[1], fmaf(b[2], b[2], fmaf(b[3], b[3], sq))));

  u32x2* d = (u32x2*)(dst + (size_t)row * (Dd / 2));
  d[t]       = (u32x2){pack2_bf16(a[0], a[1]), pack2_bf16(a[2], a[3])};
  d[256 + t] = (u32x2){pack2_bf16(b[0], b[1]), pack2_bf16(b[2], b[3])};

  #pragma unroll
  for (int m = 32; m; m >>= 1) sq += __shfl_xor(sq, m, 64);
  const int wave = t >> 6, lane = t & 63;
  if (lane == 0) red[wave] = sq;
  __syncthreads();
  if (t == 0) inv[row] = 1.0f / sqrtf(red[0] + red[1] + red[2] + red[3]);
}

// ---------------- Pass 2: bf16 GEMM — r4 counted-vmcnt version (~43us, 800 TF) ----
// FINAL: schedule-bound local optimum of the 128^2 2-phase class (MfmaUtil 29%,
// bank-conflict 0, FETCH 32.8MB). Escapes priced and rejected for THIS shape:
//   - 256^2/256x128 8-phase: 128 blocks (half CUs idle) or 1 blk/CU loses the
//     cross-block barrier overlap -> r5 measured 50.2us (regression);
//   - split-K: +67MB fp32 reduce traffic ~ +16us, cancels the MFMA gain.
// T4 counted-vmcnt: s_barrier + s_waitcnt vmcnt(8), never drain to 0 mid-loop
// (r3->r4: 44.8->42.9us, MfmaUtil 27.3->29.5%).
// T1 XCD swizzle: grid=512=8*64 bijective, XCD x <- batch x.
// XOR swizzle on 16B chunks: LDS[r][p] = G[r][p ^ (r&7)] (0 conflicts measured).
__global__ __launch_bounds__(256, 2)
void gemm_kernel(const short* __restrict__ abf, const short* __restrict__ bbf,
                 const float* __restrict__ invA, const float* __restrict__ invB,
                 float* __restrict__ out)
{
  __shared__ short As[2][BM * BK];   // 2 x 16 KB
  __shared__ short Bs[2][BN * BK];   // 2 x 16 KB

  const int bid0 = blockIdx.x;
  const int bid  = ((bid0 & 7) << 6) | (bid0 >> 3);   // T1: XCD-contiguous remap
  const int b    = bid >> 6;
  const int tile = bid & 63;
  const int tm   = tile >> 3;
  const int tn   = tile & 7;

  const int t = threadIdx.x, wave = t >> 6, lane = t & 63;

  const int srow = lane >> 3;
  const int cph  = lane & 7;
  const int r0   = wave * 32;

  const size_t aRow = (size_t)(b * Tt + tm * BM);
  const size_t bRow = (size_t)(b * Ss + tn * BN);
  const short *gA0, *gA1, *gA2, *gA3, *gB0, *gB1, *gB2, *gB3;
  {
    int r;
    r = r0 + 0 * 8 + srow; gA0 = abf + (aRow + r) * Dd + (cph ^ (r & 7)) * 8;
                           gB0 = bbf + (bRow + r) * Dd + (cph ^ (r & 7)) * 8;
    r = r0 + 1 * 8 + srow; gA1 = abf + (aRow + r) * Dd + (cph ^ (r & 7)) * 8;
                           gB1 = bbf + (bRow + r) * Dd + (cph ^ (r & 7)) * 8;
    r = r0 + 2 * 8 + srow; gA2 = abf + (aRow + r) * Dd + (cph ^ (r & 7)) * 8;
                           gB2 = bbf + (bRow + r) * Dd + (cph ^ (r & 7)) * 8;
    r = r0 + 3 * 8 + srow; gA3 = abf + (aRow + r) * Dd + (cph ^ (r & 7)) * 8;
                           gB3 = bbf + (bRow + r) * Dd + (cph ^ (r & 7)) * 8;
  }

  const int wm = (wave >> 1) << 6;
  const int wn = (wave & 1) << 6;
  const int lm = lane & 15;
  const int kq = lane >> 4;

  f32x4 acc[4][4];
  #pragma unroll
  for (int i = 0; i < 4; ++i)
    #pragma unroll
    for (int j = 0; j < 4; ++j)
      acc[i][j] = (f32x4)0.0f;

#define STAGE(bi) do {                                                   \
    gld_lds16(gA0, As[bi] + (r0 + 0)  * BK);                             \
    gld_lds16(gA1, As[bi] + (r0 + 8)  * BK);                             \
    gld_lds16(gA2, As[bi] + (r0 + 16) * BK);                             \
    gld_lds16(gA3, As[bi] + (r0 + 24) * BK);                             \
    gld_lds16(gB0, Bs[bi] + (r0 + 0)  * BK);                             \
    gld_lds16(gB1, Bs[bi] + (r0 + 8)  * BK);                             \
    gld_lds16(gB2, Bs[bi] + (r0 + 16) * BK);                             \
    gld_lds16(gB3, Bs[bi] + (r0 + 24) * BK);                             \
    gA0 += BK; gA1 += BK; gA2 += BK; gA3 += BK;                          \
    gB0 += BK; gB1 += BK; gB2 += BK; gB3 += BK;                          \
  } while (0)

#define COMPUTE(bi) do {                                                 \
    _Pragma("unroll")                                                    \
    for (int ks = 0; ks < 2; ++ks) {                                     \
      const int pchunk = ((ks * 4 + kq) ^ (lm & 7)) * 8;                 \
      s16x8 af[4], bfr[4];                                               \
      _Pragma("unroll")                                                  \
      for (int i = 0; i < 4; ++i) {                                      \
        af[i]  = *(const s16x8*)(As[bi] + (wm + i * 16 + lm) * BK + pchunk); \
        bfr[i] = *(const s16x8*)(Bs[bi] + (wn + i * 16 + lm) * BK + pchunk); \
      }                                                                  \
      _Pragma("unroll")                                                  \
      for (int mi = 0; mi < 4; ++mi)                                     \
        _Pragma("unroll")                                                \
        for (int ni = 0; ni < 4; ++ni)                                   \
          acc[mi][ni] = __builtin_amdgcn_mfma_f32_16x16x32_bf16(af[mi], bfr[ni], acc[mi][ni], 0, 0, 0); \
    }                                                                    \
  } while (0)

#define WAIT_BAR(n) do {                                                 \
    asm volatile("s_waitcnt vmcnt(" #n ")" ::: "memory");                \
    __builtin_amdgcn_s_barrier();                                        \
    __builtin_amdgcn_sched_barrier(0);                                   \
  } while (0)

  // prologue: slabs 0,1 in flight (16 outstanding)
  STAGE(0);
  STAGE(1);

  // steady: 15 iterations x 2 slabs = slabs 0..29; stages slabs 2..31.
  for (int i = 0; i < 15; ++i) {
    WAIT_BAR(8);                   // buffer0 slab landed (8 newer still flying)
    COMPUTE(0);
    __builtin_amdgcn_sched_barrier(0);
    __builtin_amdgcn_s_barrier();  // all waves done reading buffer0
    STAGE(0);                      // slab 2i+2 -> 16 outstanding
    WAIT_BAR(8);                   // buffer1 slab landed
    COMPUTE(1);
    __builtin_amdgcn_sched_barrier(0);
    __builtin_amdgcn_s_barrier();  // all waves done reading buffer1
    STAGE(1);                      // slab 2i+3 -> 16 outstanding
  }

  // epilogue: slabs 30 (buffer0), 31 (buffer1).
  WAIT_BAR(8);
  COMPUTE(0);
  WAIT_BAR(0);                     // final buffer needs a full wait
  COMPUTE(1);
#undef STAGE
#undef COMPUTE
#undef WAIT_BAR

  const float* iA = invA + b * Tt + tm * BM;
  const float* iB = invB + b * Ss + tn * BN;
  float* outb = out + (size_t)(b * Tt + tm * BM) * Ss + tn * BN;
  const int m0 = wm + kq * 4;
  const int n0 = wn + lm;
  #pragma unroll
  for (int mi = 0; mi < 4; ++mi) {
    #pragma unroll
    for (int r = 0; r < 4; ++r) {
      const int mrow = m0 + mi * 16 + r;
      const float ia = iA[mrow];
      float* orow = outb + (size_t)mrow * Ss;
      #pragma unroll
      for (int ni = 0; ni < 4; ++ni) {
        const int ncol = n0 + ni * 16;
        orow[ncol] = acc[mi][ni][r] * (ia * iB[ncol]);
      }
    }
  }
}

// ---------------- Fallback: round-1 fused kernel (used only if ws too small) ----------------
#define LDKF 40
#define BKF 32
__global__ __launch_bounds__(256, 2)
void paircos_kernel(const float* __restrict__ sup, const float* __restrict__ xh,
                    float* __restrict__ out)
{
  __shared__ short As[BM * LDKF];
  __shared__ short Bs[BN * LDKF];
  __shared__ float invA[BM];
  __shared__ float invB[BN];

  const int bid = blockIdx.x;
  const int b = bid >> 6, tile = bid & 63, tm = tile >> 3, tn = tile & 7;
  const float* Abase = xh  + (size_t)(b * Tt + tm * BM) * Dd;
  const float* Bbase = sup + (size_t)(b * Ss + tn * BN) * Dd;
  const int t = threadIdx.x, row = t >> 1, kh = t & 1;
  const f32x4* agp = (const f32x4*)(Abase + (size_t)row * Dd + kh * 16);
  const f32x4* bgp = (const f32x4*)(Bbase + (size_t)row * Dd + kh * 16);
  u32x4* awr = (u32x4*)(As + row * LDKF + kh * 16);
  u32x4* bwr = (u32x4*)(Bs + row * LDKF + kh * 16);
  const int wave = t >> 6, lane = t & 63;
  const int wm = (wave >> 1) << 6, wn = (wave & 1) << 6;
  const int lm = lane & 15, kq = lane >> 4;

  f32x4 acc[4][4];
  #pragma unroll
  for (int i = 0; i < 4; ++i)
    #pragma unroll
    for (int j = 0; j < 4; ++j) acc[i][j] = (f32x4)0.0f;
  float sqa = 0.0f, sqb = 0.0f;
  f32x4 areg[4], breg[4];
  #pragma unroll
  for (int i = 0; i < 4; ++i) { areg[i] = agp[i]; breg[i] = bgp[i]; }

  for (int k0 = 0; k0 < Dd; k0 += BKF) {
    unsigned pa[8], pb[8];
    #pragma unroll
    for (int i = 0; i < 4; ++i) {
      sqa = fmaf(areg[i][0], areg[i][0], sqa); sqa = fmaf(areg[i][1], areg[i][1], sqa);
      sqa = fmaf(areg[i][2], areg[i][2], sqa); sqa = fmaf(areg[i][3], areg[i][3], sqa);
      pa[i*2+0] = pack2_bf16(areg[i][0], areg[i][1]); pa[i*2+1] = pack2_bf16(areg[i][2], areg[i][3]);
      sqb = fmaf(breg[i][0], breg[i][0], sqb); sqb = fmaf(breg[i][1], breg[i][1], sqb);
      sqb = fmaf(breg[i][2], breg[i][2], sqb); sqb = fmaf(breg[i][3], breg[i][3], sqb);
      pb[i*2+0] = pack2_bf16(breg[i][0], breg[i][1]); pb[i*2+1] = pack2_bf16(breg[i][2], breg[i][3]);
    }
    __syncthreads();
    awr[0] = (u32x4){pa[0],pa[1],pa[2],pa[3]}; awr[1] = (u32x4){pa[4],pa[5],pa[6],pa[7]};
    bwr[0] = (u32x4){pb[0],pb[1],pb[2],pb[3]}; bwr[1] = (u32x4){pb[4],pb[5],pb[6],pb[7]};
    __syncthreads();
    if (k0 + BKF < Dd) {
      const int off = (k0 + BKF) >> 2;
      #pragma unroll
      for (int i = 0; i < 4; ++i) { areg[i] = agp[off + i]; breg[i] = bgp[off + i]; }
    }
    s16x8 af[4], bfr[4];
    #pragma unroll
    for (int i = 0; i < 4; ++i) {
      af[i]  = *(const s16x8*)(As + (wm + i*16 + lm) * LDKF + kq * 8);
      bfr[i] = *(const s16x8*)(Bs + (wn + i*16 + lm) * LDKF + kq * 8);
    }
    #pragma unroll
    for (int mi = 0; mi < 4; ++mi)
      #pragma unroll
      for (int ni = 0; ni < 4; ++ni)
        acc[mi][ni] = __builtin_amdgcn_mfma_f32_16x16x32_bf16(af[mi], bfr[ni], acc[mi][ni], 0, 0, 0);
  }
  __syncthreads();
  ((float*)As)[t] = sqa; ((float*)Bs)[t] = sqb;
  __syncthreads();
  if (t < 128) {
    invA[t] = 1.0f / sqrtf(((float*)As)[2*t] + ((float*)As)[2*t+1]);
    invB[t] = 1.0f / sqrtf(((float*)Bs)[2*t] + ((float*)Bs)[2*t+1]);
  }
  __syncthreads();
  float* outb = out + (size_t)(b * Tt + tm * BM) * Ss + tn * BN;
  const int m0 = wm + kq * 4, n0 = wn + lm;
  #pragma unroll
  for (int mi = 0; mi < 4; ++mi) {
    #pragma unroll
    for (int r = 0; r < 4; ++r) {
      const int mrow = m0 + mi * 16 + r;
      const float ia = invA[mrow];
      float* orow = outb + (size_t)mrow * Ss;
      #pragma unroll
      for (int ni = 0; ni < 4; ++ni) {
        const int ncol = n0 + ni * 16;
        orow[ncol] = acc[mi][ni][r] * (ia * invB[ncol]);
      }
    }
  }
}

extern "C" void kernel_launch(void* const* d_in, const int* in_sizes, int n_in,
                              void* d_out, int out_size, void* d_ws, size_t ws_size,
                              hipStream_t stream) {
  const float* sup = (const float*)d_in[0];  // support_sets [8,1024,2048]
  const float* xh  = (const float*)d_in[1];  // X_hats       [8,1024,2048]
  float* out = (float*)d_out;                // [8,1024,1024] fp32

  const size_t nElem = (size_t)Bb * Tt * Dd;              // 16.78M per tensor
  const size_t bfBytes = nElem * sizeof(short);           // 33.55 MB
  const size_t NEED = 2 * bfBytes + 2 * (size_t)Bb * Tt * sizeof(float);

  if (ws_size >= NEED) {
    unsigned* abf = (unsigned*)d_ws;
    unsigned* bbf = (unsigned*)((char*)d_ws + bfBytes);
    float* invA = (float*)((char*)d_ws + 2 * bfBytes);
    float* invB = invA + (size_t)Bb * Tt;
    convert_kernel<<<dim3(16384), dim3(256), 0, stream>>>(sup, xh, abf, bbf, invA, invB);
    gemm_kernel<<<dim3(512), dim3(256), 0, stream>>>((const short*)abf, (const short*)bbf,
                                                     invA, invB, out);
  } else {
    paircos_kernel<<<dim3(512), dim3(256), 0, stream>>>(sup, xh, out);
  }
}